// Round 1
// baseline (449.048 us; speedup 1.0000x reference)
//
#include <hip/hip_runtime.h>

// Element-wise 16-step spiking recurrence.
//   v = x; z = 0; out = 0
//   for t in 0..15: v -= z*h[t]; z = (v - T[t])/(|v|+1) > 0; out += z*d[t]
// |v|+1 > 0  =>  spike condition is exactly (v > T[t]) -> no divide.
// z in {0,1} so fmaf(-z,h,v) rounds identically to the reference's v - z*h.
//
// R1 change vs R0 (444 us): 2 float4 per thread instead of 1.
//   - Both 16B loads issue back-to-back before any compute -> 2 KiB in flight
//     per wave (was 1 KiB), doubling per-wave MLP for the HBM round trip.
//   - 8 independent recurrence chains per thread (was 4) -> more ILP across
//     the dependent fma -> v_cmp -> v_cndmask -> fma chain.
//   - VGPR stays ~40 (<64) so occupancy holds at 8 waves/SIMD.
// Grid: 32768 blocks x 256 threads x 2 float4 = 16,777,216 float4 = exact cover.
// x and out are each touched exactly once -> nontemporal load/store.

typedef float floatv4 __attribute__((ext_vector_type(4)));

__global__ __launch_bounds__(256) void spike_recurrence_kernel(
    const float* __restrict__ x,
    const float* __restrict__ h,
    const float* __restrict__ d,
    const float* __restrict__ T,
    float* __restrict__ out,
    int n4)
{
    // Wave-uniform constant loads -> scalar loads into SGPRs.
    float hh[16], dd[16], tt[16];
#pragma unroll
    for (int t = 0; t < 16; ++t) {
        hh[t] = h[t];
        dd[t] = d[t];
        tt[t] = T[t];
    }

    const floatv4* __restrict__ x4 = reinterpret_cast<const floatv4*>(x);
    floatv4* __restrict__ o4 = reinterpret_cast<floatv4*>(out);

    // Two coalesced segments per block: [base, base+255] and [base+256, base+511].
    int base = blockIdx.x * (256 * 2) + threadIdx.x;
    int i0 = base;
    int i1 = base + 256;
    bool p0 = i0 < n4;
    bool p1 = i1 < n4;

    floatv4 xv0 = {0.f, 0.f, 0.f, 0.f};
    floatv4 xv1 = {0.f, 0.f, 0.f, 0.f};
    if (p0) xv0 = __builtin_nontemporal_load(&x4[i0]);   // streamed, read once
    if (p1) xv1 = __builtin_nontemporal_load(&x4[i1]);   // issued before compute

    float v[8], z[8], o[8];
#pragma unroll
    for (int j = 0; j < 4; ++j) {
        v[j]     = xv0[j];
        v[4 + j] = xv1[j];
        z[j] = z[4 + j] = 0.f;
        o[j] = o[4 + j] = 0.f;
    }

#pragma unroll
    for (int t = 0; t < 16; ++t) {
#pragma unroll
        for (int j = 0; j < 8; ++j) {
            v[j] = fmaf(-z[j], hh[t], v[j]);      // v -= z*h[t] (exact: z in {0,1})
            z[j] = (v[j] > tt[t]) ? 1.0f : 0.0f;  // sign((v-T)/(|v|+1)) == sign(v-T)
            o[j] = fmaf(z[j], dd[t], o[j]);       // out += z*d[t]
        }
    }

    floatv4 ov0 = {o[0], o[1], o[2], o[3]};
    floatv4 ov1 = {o[4], o[5], o[6], o[7]};
    if (p0) __builtin_nontemporal_store(ov0, &o4[i0]);   // streaming store, no re-read
    if (p1) __builtin_nontemporal_store(ov1, &o4[i1]);
}

extern "C" void kernel_launch(void* const* d_in, const int* in_sizes, int n_in,
                              void* d_out, int out_size, void* d_ws, size_t ws_size,
                              hipStream_t stream) {
    const float* x = (const float*)d_in[0];
    const float* h = (const float*)d_in[1];
    const float* d = (const float*)d_in[2];
    const float* T = (const float*)d_in[3];
    float* out = (float*)d_out;

    int n = in_sizes[0];          // 4*4096*4096 = 67,108,864 (divisible by 4)
    int n4 = n / 4;               // 16,777,216 float4 groups

    const int PER_BLOCK = 256 * 2;                  // 2 float4 per thread
    int block = 256;
    int grid = (n4 + PER_BLOCK - 1) / PER_BLOCK;    // 32768 blocks, exact cover
    spike_recurrence_kernel<<<grid, block, 0, stream>>>(x, h, d, T, out, n4);
}

// Round 2
// 437.131 us; speedup vs baseline: 1.0273x; 1.0273x over previous
//
#include <hip/hip_runtime.h>

// Element-wise 16-step spiking recurrence.
//   v = x; z = 0; out = 0
//   for t in 0..15: v -= z*h[t]; z = (v - T[t])/(|v|+1) > 0; out += z*d[t]
// |v|+1 > 0  =>  spike condition is exactly (v > T[t]) -> no divide.
// z in {0,1} so fmaf(-z,h,v) rounds identically to the reference's v - z*h.
//
// R2 change vs R1 (449 us): REMOVE nontemporal hints — pure A/B on NT.
//   Theory: inferred kernel BW ~4.5 TB/s vs 6.3 TB/s plain-copy ceiling;
//   the only nonstandard element in the memory path was nt load/store.
//   The 537 MB stream >> 32 MB L2, so cache pollution is a non-issue;
//   plain accesses use the same path as the 6.5 TB/s harness fill and the
//   6.29 TB/s m13 copy microbenchmark.
// Everything else identical to R1: 2 float4/thread, loads issued before
// compute, 8 independent chains, 32768 blocks x 256 threads, exact cover.

typedef float floatv4 __attribute__((ext_vector_type(4)));

__global__ __launch_bounds__(256) void spike_recurrence_kernel(
    const float* __restrict__ x,
    const float* __restrict__ h,
    const float* __restrict__ d,
    const float* __restrict__ T,
    float* __restrict__ out,
    int n4)
{
    // Wave-uniform constant loads -> scalar loads into SGPRs.
    float hh[16], dd[16], tt[16];
#pragma unroll
    for (int t = 0; t < 16; ++t) {
        hh[t] = h[t];
        dd[t] = d[t];
        tt[t] = T[t];
    }

    const floatv4* __restrict__ x4 = reinterpret_cast<const floatv4*>(x);
    floatv4* __restrict__ o4 = reinterpret_cast<floatv4*>(out);

    // Two coalesced segments per block: [base, base+255] and [base+256, base+511].
    int base = blockIdx.x * (256 * 2) + threadIdx.x;
    int i0 = base;
    int i1 = base + 256;
    bool p0 = i0 < n4;
    bool p1 = i1 < n4;

    floatv4 xv0 = {0.f, 0.f, 0.f, 0.f};
    floatv4 xv1 = {0.f, 0.f, 0.f, 0.f};
    if (p0) xv0 = x4[i0];   // plain load (R2: no nt hint)
    if (p1) xv1 = x4[i1];   // issued before compute

    float v[8], z[8], o[8];
#pragma unroll
    for (int j = 0; j < 4; ++j) {
        v[j]     = xv0[j];
        v[4 + j] = xv1[j];
        z[j] = z[4 + j] = 0.f;
        o[j] = o[4 + j] = 0.f;
    }

#pragma unroll
    for (int t = 0; t < 16; ++t) {
#pragma unroll
        for (int j = 0; j < 8; ++j) {
            v[j] = fmaf(-z[j], hh[t], v[j]);      // v -= z*h[t] (exact: z in {0,1})
            z[j] = (v[j] > tt[t]) ? 1.0f : 0.0f;  // sign((v-T)/(|v|+1)) == sign(v-T)
            o[j] = fmaf(z[j], dd[t], o[j]);       // out += z*d[t]
        }
    }

    floatv4 ov0 = {o[0], o[1], o[2], o[3]};
    floatv4 ov1 = {o[4], o[5], o[6], o[7]};
    if (p0) o4[i0] = ov0;   // plain store (R2: no nt hint)
    if (p1) o4[i1] = ov1;
}

extern "C" void kernel_launch(void* const* d_in, const int* in_sizes, int n_in,
                              void* d_out, int out_size, void* d_ws, size_t ws_size,
                              hipStream_t stream) {
    const float* x = (const float*)d_in[0];
    const float* h = (const float*)d_in[1];
    const float* d = (const float*)d_in[2];
    const float* T = (const float*)d_in[3];
    float* out = (float*)d_out;

    int n = in_sizes[0];          // 4*4096*4096 = 67,108,864 (divisible by 4)
    int n4 = n / 4;               // 16,777,216 float4 groups

    const int PER_BLOCK = 256 * 2;                  // 2 float4 per thread
    int block = 256;
    int grid = (n4 + PER_BLOCK - 1) / PER_BLOCK;    // 32768 blocks, exact cover
    spike_recurrence_kernel<<<grid, block, 0, stream>>>(x, h, d, T, out, n4);
}